// Round 2
// baseline (70.040 us; speedup 1.0000x reference)
//
#include <hip/hip_runtime.h>
#include <hip/hip_bf16.h>

// Problem constants (from reference)
#define UNITS 512
#define CONN  512
#define SEQL  32

typedef __hip_bfloat16 bf16;
typedef __attribute__((ext_vector_type(8))) short short8;   // 8 bf16 = MFMA A/B frag
typedef __attribute__((ext_vector_type(4))) float floatx4;  // MFMA C/D frag

// out[b,u] = relu( sum_c x[b,c] * kernel[u] * dendriticW[dendrites[u,c], u] + bias[u] )
// == 512^3 GEMM with gather-built weights, bf16 MFMA (absmax 1.95e-3 vs 9.84e-3).
//
// R7: occupancy probe/fix. R6 (single fused kernel, no ws) == R5 (two kernels,
// ws round-trip) within noise -> either harness-overhead floor or BOTH are
// latency-bound at exactly 1 wave/SIMD (1024 waves / 1024 SIMDs, zero TLP).
// This version: 4-way K-split. Grid (32,32)=1024 blocks x 4 waves; each wave
// does a K=128 quarter (4 MFMAs) of one 16x16 tile; LDS reduce of partials.
// -> 4096 waves = 4/SIMD, per-wave global-load chain quartered, dend int4s
// preloaded to registers so their latency hides under the table build.
// W-tile build + B layout + MFMA maps copied verbatim from the proven R6.

union cv8 { bf16 h[8]; short8 v; };

__device__ __forceinline__ short8 cvt8(const float* p) {
    const float4 f0 = ((const float4*)p)[0];
    const float4 f1 = ((const float4*)p)[1];
    cv8 a;
    a.h[0] = __float2bfloat16(f0.x); a.h[1] = __float2bfloat16(f0.y);
    a.h[2] = __float2bfloat16(f0.z); a.h[3] = __float2bfloat16(f0.w);
    a.h[4] = __float2bfloat16(f1.x); a.h[5] = __float2bfloat16(f1.y);
    a.h[6] = __float2bfloat16(f1.z); a.h[7] = __float2bfloat16(f1.w);
    return a.v;
}

// Grid: (UNITS/16, batch/16), 256 threads = 4 waves. Block: one 16x16 output
// tile; wave wv covers K in [wv*128, wv*128+128).
__global__ __launch_bounds__(256) void dendriter_v3(
    const float* __restrict__ x,     // [batch*CONN] fp32
    const float* __restrict__ kern,  // [UNITS] fp32
    const float* __restrict__ dW,    // [SEQL*UNITS] fp32
    const float* __restrict__ bias,  // [UNITS] fp32
    const int*   __restrict__ dend,  // [UNITS*CONN] int32
    float* __restrict__ out)         // [batch*UNITS] fp32
{
    __shared__ float   table[16][SEQL];  // kv*dW column per tile-unit (2 KB)
    __shared__ short8  wl[16][65];       // bf16 W tile 16u x 512c (16.6 KB)
    __shared__ floatx4 red[3][64];       // K-split partials (3 KB)

    const int t    = threadIdx.x;
    const int ut   = blockIdx.x * 16;
    const int bt   = blockIdx.y * 16;
    const int lane = t & 63;
    const int wv   = t >> 6;             // K-quarter id 0..3
    const int m    = lane & 15;          // A batch-row / C unit-col
    const int q    = lane >> 4;          // k sub-offset / C row-group

    // ---- preload this wave's 4 A-fragments (K window) ----
    const float* xrow = x + (size_t)(bt + m) * CONN + q * 8;
    short8 afr[4];
#pragma unroll
    for (int j = 0; j < 4; ++j)
        afr[j] = cvt8(xrow + (wv * 4 + j) * 32);

    // ---- preload dend int4s to registers (latency hides under table build) ----
    const int ul  = t >> 4;              // unit 0..15 (4 per wave)
    const int cg0 = (t & 15) * 4;        // 4 column-groups of 8 conns
    const int4* dp = (const int4*)(dend + (size_t)(ut + ul) * CONN + cg0 * 8);
    int4 sreg[8];
#pragma unroll
    for (int j = 0; j < 8; ++j) sreg[j] = dp[j];

    // ---- dW table: coalesced 2 KB, kv folded in ----
#pragma unroll
    for (int e = t; e < 16 * SEQL; e += 256) {   // 2 iters
        const int seg = e >> 4, uu = e & 15;
        table[uu][seg] = kern[ut + uu] * dW[seg * UNITS + ut + uu];
    }
    __syncthreads();

    // ---- W tile build from registers + LDS table (proven layout) ----
#pragma unroll
    for (int j = 0; j < 4; ++j) {
        const int4 s0 = sreg[2 * j];
        const int4 s1 = sreg[2 * j + 1];
        const int segs[8] = {s0.x, s0.y, s0.z, s0.w, s1.x, s1.y, s1.z, s1.w};
        cv8 w;
#pragma unroll
        for (int i = 0; i < 8; ++i)
            w.h[i] = __float2bfloat16(table[ul][segs[i]]);
        const int cg = cg0 + j;
        wl[cg >> 2][ul | ((cg & 3) << 4)] = w.v;
    }
    __syncthreads();

    // ---- 4 MFMAs over this wave's K window ----
    floatx4 acc = {0.f, 0.f, 0.f, 0.f};
#pragma unroll
    for (int j = 0; j < 4; ++j)
        acc = __builtin_amdgcn_mfma_f32_16x16x32_bf16(afr[j],
                  wl[wv * 4 + j][lane], acc, 0, 0, 0);

    // ---- cross-wave K reduce ----
    if (wv) red[wv - 1][lane] = acc;
    __syncthreads();
    if (wv == 0) {
        acc += red[0][lane];
        acc += red[1][lane];
        acc += red[2][lane];
        const float bu = bias[ut + m];
#pragma unroll
        for (int r = 0; r < 4; ++r) {
            float v = acc[r] + bu;
            v = v > 0.f ? v : 0.f;
            out[(size_t)(bt + q * 4 + r) * UNITS + ut + m] = v;
        }
    }
}

extern "C" void kernel_launch(void* const* d_in, const int* in_sizes, int n_in,
                              void* d_out, int out_size, void* d_ws, size_t ws_size,
                              hipStream_t stream) {
    // setup_inputs() order: x, kernel, dendriticW, bias, dendrites — all fp32
    const float* x    = (const float*)d_in[0];
    const float* kern = (const float*)d_in[1];
    const float* dW   = (const float*)d_in[2];
    const float* bias = (const float*)d_in[3];
    const int*   dend = (const int*)  d_in[4];
    float* out = (float*)d_out;

    const int batch = in_sizes[0] / CONN;   // 512
    (void)d_ws; (void)ws_size;              // ws unused (poison fill is unconditional)

    dendriter_v3<<<dim3(UNITS / 16, batch / 16), 256, 0, stream>>>(
        x, kern, dW, bias, dend, out);
}

// Round 3
// 66.672 us; speedup vs baseline: 1.0505x; 1.0505x over previous
//
#include <hip/hip_runtime.h>
#include <hip/hip_bf16.h>

// Problem constants (from reference)
#define UNITS 512
#define CONN  512
#define SEQL  32

typedef __hip_bfloat16 bf16;
typedef __attribute__((ext_vector_type(8))) short short8;   // 8 bf16 = MFMA A/B frag
typedef __attribute__((ext_vector_type(4))) float floatx4;  // MFMA C/D frag

// out[b,u] = relu( sum_c x[b,c] * kernel[u] * dendriticW[dendrites[u,c], u] + bias[u] )
// == 512^3 GEMM with gather-built weights, bf16 MFMA (absmax 1.95e-3 vs 9.84e-3).
//
// R8 = revert to R6 structure (best fill-normalized residual: R5 25.6, R6 25.7,
// R7 29.8 us) + R7's one good micro-change: dend int4s hoisted to registers
// BEFORE the table build so their global latency overlaps the table phase.
// Fill-normalized evidence says the ~25.5 us residual is ~21 us fixed harness
// dispatch overhead + ~4-5 us kernel; R7's K-split regression was its 4x dend
// refetch + redundant W builds, not occupancy.

union cv8 { bf16 h[8]; short8 v; };

__device__ __forceinline__ short8 cvt8(const float* p) {
    const float4 f0 = ((const float4*)p)[0];
    const float4 f1 = ((const float4*)p)[1];
    cv8 a;
    a.h[0] = __float2bfloat16(f0.x); a.h[1] = __float2bfloat16(f0.y);
    a.h[2] = __float2bfloat16(f0.z); a.h[3] = __float2bfloat16(f0.w);
    a.h[4] = __float2bfloat16(f1.x); a.h[5] = __float2bfloat16(f1.y);
    a.h[6] = __float2bfloat16(f1.z); a.h[7] = __float2bfloat16(f1.w);
    return a.v;
}

// Grid: (UNITS/16, batch/64), 256 threads = 4 waves. Each block: 16 units x
// 64 batch rows. Each wave: one 16x16 output tile over K=512 (16 MFMAs).
__global__ __launch_bounds__(256) void dendriter_fused_v4(
    const float* __restrict__ x,     // [batch*CONN] fp32
    const float* __restrict__ kern,  // [UNITS] fp32 (per-unit scalar)
    const float* __restrict__ dW,    // [SEQL*UNITS] fp32
    const float* __restrict__ bias,  // [UNITS] fp32
    const int*   __restrict__ dend,  // [UNITS*CONN] int32 segment ids
    float* __restrict__ out)         // [batch*UNITS] fp32
{
    __shared__ float  table[16][SEQL];  // kv*dW column per tile-unit (2 KB)
    __shared__ short8 wl[16][65];       // bf16 W tile: 16 units x 512 conns (16.6 KB)

    const int t  = threadIdx.x;
    const int ut = blockIdx.x * 16;
    const int bt = blockIdx.y * 64;

    // ---- A preload: issue all x loads first; latency hides under W build ----
    const int lane = t & 63;
    const int wv   = t >> 6;            // wave id 0..3 -> batch sub-tile
    const int m    = lane & 15;         // A row / C unit-col (m89-verified maps)
    const int q    = lane >> 4;         // k-quarter / C row-group
    const int btw  = bt + wv * 16;
    const float* xrow = x + (size_t)(btw + m) * CONN + q * 8;
    short8 afr[16];
#pragma unroll
    for (int kb = 0; kb < 16; ++kb)
        afr[kb] = cvt8(xrow + kb * 32);     // 64 VGPRs, held across barriers

    // ---- dend preload to registers (R7-verified): latency overlaps table ----
    const int ul  = t >> 4;                  // unit 0..15
    const int cg0 = (t & 15) * 4;            // 4 column-groups of 8 conns
    const int4* dp = (const int4*)(dend + (size_t)(ut + ul) * CONN + cg0 * 8);
    int4 sreg[8];
#pragma unroll
    for (int j = 0; j < 8; ++j) sreg[j] = dp[j];

    // ---- dW table: coalesced 2 KB load, kv folded in ----
#pragma unroll
    for (int e = t; e < 16 * SEQL; e += 256) {   // 2 iters
        const int seg = e >> 4, uu = e & 15;     // consecutive t -> consecutive u
        table[uu][seg] = kern[ut + uu] * dW[seg * UNITS + ut + uu];
    }
    __syncthreads();

    // ---- W tile build from registers + LDS table (R5/R6-proven layout) ----
#pragma unroll
    for (int j = 0; j < 4; ++j) {
        const int4 s0 = sreg[2 * j];
        const int4 s1 = sreg[2 * j + 1];
        const int segs[8] = {s0.x, s0.y, s0.z, s0.w, s1.x, s1.y, s1.z, s1.w};
        cv8 w;
#pragma unroll
        for (int i = 0; i < 8; ++i)          // LDS lookup, ~2-way banks (free)
            w.h[i] = __float2bfloat16(table[ul][segs[i]]);
        const int cg = cg0 + j;
        wl[cg >> 2][ul | ((cg & 3) << 4)] = w.v;   // proven B layout
    }
    __syncthreads();

    // ---- MFMA: B read wl[kb][lane] is exactly 2-way banked (free) ----
    floatx4 acc = {0.f, 0.f, 0.f, 0.f};
#pragma unroll
    for (int kb = 0; kb < 16; ++kb)
        acc = __builtin_amdgcn_mfma_f32_16x16x32_bf16(afr[kb], wl[kb][lane],
                                                      acc, 0, 0, 0);

    // ---- epilogue: bias + relu, C/D map col=lane&15(unit), row=q*4+r(batch) ----
    const float bu = bias[ut + m];
#pragma unroll
    for (int r = 0; r < 4; ++r) {
        float v = acc[r] + bu;
        v = v > 0.f ? v : 0.f;
        out[(size_t)(btw + q * 4 + r) * UNITS + ut + m] = v;
    }
}

extern "C" void kernel_launch(void* const* d_in, const int* in_sizes, int n_in,
                              void* d_out, int out_size, void* d_ws, size_t ws_size,
                              hipStream_t stream) {
    // setup_inputs() order: x, kernel, dendriticW, bias, dendrites — all fp32
    const float* x    = (const float*)d_in[0];
    const float* kern = (const float*)d_in[1];
    const float* dW   = (const float*)d_in[2];
    const float* bias = (const float*)d_in[3];
    const int*   dend = (const int*)  d_in[4];
    float* out = (float*)d_out;

    const int batch = in_sizes[0] / CONN;   // 512
    (void)d_ws; (void)ws_size;              // ws unused (poison fill is unconditional)

    dendriter_fused_v4<<<dim3(UNITS / 16, batch / 64), 256, 0, stream>>>(
        x, kern, dW, bias, dend, out);
}